// Round 1
// baseline (48.861 us; speedup 1.0000x reference)
//
#include <hip/hip_runtime.h>

#define NPART 128
#define NDIM  128
#define BATCH 4096

// 1 block / 64 threads: softmax over logp[128] -> p[128] in workspace
__global__ void softmax128_kernel(const float* __restrict__ logp,
                                  float* __restrict__ p) {
    int lane = threadIdx.x;              // 64 lanes, each owns 2 elements
    float a = logp[lane];
    float b = logp[lane + 64];
    float m = fmaxf(a, b);
    #pragma unroll
    for (int off = 32; off > 0; off >>= 1)
        m = fmaxf(m, __shfl_xor(m, off));
    float ea = expf(a - m);
    float eb = expf(b - m);
    float s = ea + eb;
    #pragma unroll
    for (int off = 32; off > 0; off >>= 1)
        s += __shfl_xor(s, off);
    float inv = 1.0f / s;
    p[lane]      = ea * inv;
    p[lane + 64] = eb * inv;
}

// One block per batch sample; thread i computes out[b,i].
__global__ __launch_bounds__(NDIM)
void mixture_kernel(const float* __restrict__ gaussian,   // [BATCH, NDIM]
                    const float* __restrict__ pos,        // [NPART, NDIM]
                    const float* __restrict__ sigma,      // [NPART, NDIM, NDIM]
                    const int*   __restrict__ randind,    // [BATCH]
                    const float* __restrict__ p,          // [NPART] softmax
                    float* __restrict__ out,              // [BATCH*NDIM]
                    float* __restrict__ wout,             // [BATCH]
                    float* __restrict__ indout) {         // [BATCH]
    const int b = blockIdx.x;
    const int i = threadIdx.x;
    const int ind = randind[b];

    __shared__ float y[NDIM];
    y[i] = gaussian[b * NDIM + i];
    __syncthreads();

    const float4* s4 = reinterpret_cast<const float4*>(
        sigma + ((size_t)ind * NDIM + i) * NDIM);
    const float4* y4 = reinterpret_cast<const float4*>(y);

    float acc = 0.0f;
    #pragma unroll
    for (int j = 0; j < NDIM / 4; ++j) {
        float4 sv = s4[j];
        float4 yv = y4[j];   // same address across all lanes -> LDS broadcast
        acc += sv.x * yv.x + sv.y * yv.y + sv.z * yv.z + sv.w * yv.w;
    }

    out[b * NDIM + i] = pos[ind * NDIM + i] + acc;

    if (i == 0) {
        wout[b]   = p[ind];
        indout[b] = (float)ind;   // exact for 0..127
    }
}

extern "C" void kernel_launch(void* const* d_in, const int* in_sizes, int n_in,
                              void* d_out, int out_size, void* d_ws, size_t ws_size,
                              hipStream_t stream) {
    const float* gaussian = (const float*)d_in[0];   // [4096,128]
    const float* logp     = (const float*)d_in[1];   // [128,1]
    const float* pos      = (const float*)d_in[2];   // [128,128]
    const float* sigma    = (const float*)d_in[3];   // [128,128,128]
    const int*   randind  = (const int*)d_in[4];     // [4096]

    float* out    = (float*)d_out;            // [4096*128]
    float* wout   = out + BATCH * NDIM;       // [4096]
    float* indout = wout + BATCH;             // [4096]

    float* p = (float*)d_ws;                  // [128] softmax probs

    softmax128_kernel<<<1, 64, 0, stream>>>(logp, p);
    mixture_kernel<<<BATCH, NDIM, 0, stream>>>(gaussian, pos, sigma, randind, p,
                                               out, wout, indout);
}

// Round 2
// 43.359 us; speedup vs baseline: 1.1269x; 1.1269x over previous
//
#include <hip/hip_runtime.h>

#define NPART 128
#define NDIM  128
#define BATCH 4096
#define SPB   4                       // samples per block
#define NBLK  (BATCH / SPB)           // 1024
#define NXCD  8

// ---------------------------------------------------------------------------
// Prep kernel (1 block, 256 threads): softmax(logp) -> p (ws), counting-sort
// randind -> list (ws), and writes weights + randind-as-float outputs.
// ---------------------------------------------------------------------------
__global__ __launch_bounds__(256)
void prep_kernel(const float* __restrict__ logp,
                 const int*   __restrict__ randind,
                 float* __restrict__ p_out,     // ws: [128]
                 int*   __restrict__ list,      // ws: [4096] sorted sample ids
                 float* __restrict__ wout,      // d_out + 4096*128
                 float* __restrict__ indout) {  // d_out + 4096*128 + 4096
    __shared__ float p[NPART];
    __shared__ int   cnt[NPART];
    __shared__ int   off[NPART];
    const int t = threadIdx.x;

    if (t < 64) {                      // softmax over 128 by one wave
        float a = logp[t], b = logp[t + 64];
        float m = fmaxf(a, b);
        #pragma unroll
        for (int o = 32; o > 0; o >>= 1) m = fmaxf(m, __shfl_xor(m, o));
        float ea = expf(a - m), eb = expf(b - m);
        float s = ea + eb;
        #pragma unroll
        for (int o = 32; o > 0; o >>= 1) s += __shfl_xor(s, o);
        float inv = 1.0f / s;
        p[t] = ea * inv;  p[t + 64] = eb * inv;
        p_out[t] = p[t];  p_out[t + 64] = p[t + 64];
    }
    if (t < NPART) cnt[t] = 0;
    __syncthreads();

    for (int b = t; b < BATCH; b += 256)
        atomicAdd(&cnt[randind[b]], 1);
    __syncthreads();

    if (t == 0) {                      // exclusive prefix (128 adds, trivial)
        int acc = 0;
        for (int i = 0; i < NPART; ++i) { off[i] = acc; acc += cnt[i]; }
    }
    __syncthreads();
    if (t < NPART) cnt[t] = off[t];    // cnt reused as cursor
    __syncthreads();

    for (int b = t; b < BATCH; b += 256) {
        int ind = randind[b];
        int pos = atomicAdd(&cnt[ind], 1);
        list[pos] = b;
        wout[b]   = p[ind];
        indout[b] = (float)ind;        // exact for 0..127
    }
}

// ---------------------------------------------------------------------------
// Compute kernel: 1024 blocks x 128 threads, 4 sorted samples per block.
// Thread i computes out[b, i] for each of the block's samples; a sigma row
// float4 fetched once serves all 4 (same particle in the common case).
// ---------------------------------------------------------------------------
__global__ __launch_bounds__(NDIM)
void mix_kernel(const float* __restrict__ gaussian,  // [BATCH, NDIM]
                const float* __restrict__ pos,       // [NPART, NDIM]
                const float* __restrict__ sigma,     // [NPART, NDIM, NDIM]
                const int*   __restrict__ randind,   // [BATCH]
                const int*   __restrict__ list,      // [BATCH] sorted ids
                float* __restrict__ out) {           // [BATCH, NDIM]
    const int g = blockIdx.x;
    // XCD-chunked bijective swizzle (NBLK % NXCD == 0): each XCD gets a
    // contiguous chunk of the sorted order -> ~16 particles ~1MB, L2-resident.
    const int cpx = NBLK / NXCD;
    const int sg  = (g % NXCD) * cpx + g / NXCD;
    const int p0  = sg * SPB;
    const int i   = threadIdx.x;

    // uniform (blockIdx-only) loads -> scalarized by compiler
    const int sid0 = list[p0 + 0], sid1 = list[p0 + 1];
    const int sid2 = list[p0 + 2], sid3 = list[p0 + 3];
    const int ind0 = randind[sid0], ind1 = randind[sid1];
    const int ind2 = randind[sid2], ind3 = randind[sid3];

    __shared__ float y[SPB][NDIM];
    y[0][i] = gaussian[sid0 * NDIM + i];
    y[1][i] = gaussian[sid1 * NDIM + i];
    y[2][i] = gaussian[sid2 * NDIM + i];
    y[3][i] = gaussian[sid3 * NDIM + i];
    __syncthreads();

    const float4* y40 = reinterpret_cast<const float4*>(y[0]);
    const float4* y41 = reinterpret_cast<const float4*>(y[1]);
    const float4* y42 = reinterpret_cast<const float4*>(y[2]);
    const float4* y43 = reinterpret_cast<const float4*>(y[3]);

    float acc0 = 0.f, acc1 = 0.f, acc2 = 0.f, acc3 = 0.f;

    if (ind0 == ind3) {  // sorted => all four equal: fast path (~88% of blocks)
        const float4* row = reinterpret_cast<const float4*>(
            sigma + ((size_t)ind0 * NDIM + i) * NDIM);
        #pragma unroll
        for (int jb = 0; jb < NDIM / 4; ++jb) {
            float4 sv = row[jb];
            float4 a = y40[jb], b = y41[jb], c = y42[jb], d = y43[jb];
            acc0 += sv.x * a.x + sv.y * a.y + sv.z * a.z + sv.w * a.w;
            acc1 += sv.x * b.x + sv.y * b.y + sv.z * b.z + sv.w * b.w;
            acc2 += sv.x * c.x + sv.y * c.y + sv.z * c.z + sv.w * c.w;
            acc3 += sv.x * d.x + sv.y * d.y + sv.z * d.z + sv.w * d.w;
        }
    } else {             // bucket boundary: per-sample rows
        const int   inds[SPB] = {ind0, ind1, ind2, ind3};
        const float4* ys[SPB] = {y40, y41, y42, y43};
        float accs[SPB] = {0.f, 0.f, 0.f, 0.f};
        for (int k = 0; k < SPB; ++k) {
            const float4* row = reinterpret_cast<const float4*>(
                sigma + ((size_t)inds[k] * NDIM + i) * NDIM);
            float a = 0.f;
            #pragma unroll
            for (int jb = 0; jb < NDIM / 4; ++jb) {
                float4 sv = row[jb];
                float4 yv = ys[k][jb];
                a += sv.x * yv.x + sv.y * yv.y + sv.z * yv.z + sv.w * yv.w;
            }
            accs[k] = a;
        }
        acc0 = accs[0]; acc1 = accs[1]; acc2 = accs[2]; acc3 = accs[3];
    }

    out[sid0 * NDIM + i] = pos[ind0 * NDIM + i] + acc0;
    out[sid1 * NDIM + i] = pos[ind1 * NDIM + i] + acc1;
    out[sid2 * NDIM + i] = pos[ind2 * NDIM + i] + acc2;
    out[sid3 * NDIM + i] = pos[ind3 * NDIM + i] + acc3;
}

extern "C" void kernel_launch(void* const* d_in, const int* in_sizes, int n_in,
                              void* d_out, int out_size, void* d_ws, size_t ws_size,
                              hipStream_t stream) {
    const float* gaussian = (const float*)d_in[0];   // [4096,128]
    const float* logp     = (const float*)d_in[1];   // [128,1]
    const float* pos      = (const float*)d_in[2];   // [128,128]
    const float* sigma    = (const float*)d_in[3];   // [128,128,128]
    const int*   randind  = (const int*)d_in[4];     // [4096]

    float* out    = (float*)d_out;            // [4096*128]
    float* wout   = out + BATCH * NDIM;       // [4096]
    float* indout = wout + BATCH;             // [4096]

    float* p    = (float*)d_ws;               // [128]
    int*   list = (int*)((float*)d_ws + NPART); // [4096]

    prep_kernel<<<1, 256, 0, stream>>>(logp, randind, p, list, wout, indout);
    mix_kernel<<<NBLK, NDIM, 0, stream>>>(gaussian, pos, sigma, randind, list, out);
}

// Round 4
// 33.152 us; speedup vs baseline: 1.4739x; 1.3079x over previous
//
#include <hip/hip_runtime.h>

#define NPART 128
#define NDIM  128
#define BATCH 4096
#define SPB   2                       // samples per block
#define NBLK  (BATCH / SPB)           // 2048
#define NXCD  8

// ---------------------------------------------------------------------------
// Prep (1 block, 256 threads): softmax(logp) -> weights output, counting-sort
// randind into packed list[(sid<<7)|ind], parallel LDS scan.
// ---------------------------------------------------------------------------
__global__ __launch_bounds__(256)
void prep_kernel(const float* __restrict__ logp,
                 const int*   __restrict__ randind,
                 int*   __restrict__ list,      // ws: [4096] packed (sid<<7)|ind
                 float* __restrict__ wout,      // d_out + 4096*128
                 float* __restrict__ indout) {  // d_out + 4096*128 + 4096
    __shared__ float p[NPART];
    __shared__ int   cnt[NPART];
    __shared__ int   incl[NPART];
    __shared__ int   cursor[NPART];
    const int t = threadIdx.x;

    if (t < 64) {                      // softmax over 128 by one wave
        float a = logp[t], b = logp[t + 64];
        float m = fmaxf(a, b);
        #pragma unroll
        for (int o = 32; o > 0; o >>= 1) m = fmaxf(m, __shfl_xor(m, o));
        float ea = expf(a - m), eb = expf(b - m);
        float s = ea + eb;
        #pragma unroll
        for (int o = 32; o > 0; o >>= 1) s += __shfl_xor(s, o);
        float inv = 1.0f / s;
        p[t] = ea * inv;  p[t + 64] = eb * inv;
    }
    if (t < NPART) cnt[t] = 0;
    __syncthreads();

    for (int b = t; b < BATCH; b += 256)
        atomicAdd(&cnt[randind[b]], 1);
    __syncthreads();

    // parallel inclusive scan (Hillis-Steele) over 128 counts
    if (t < NPART) incl[t] = cnt[t];
    __syncthreads();
    #pragma unroll
    for (int d = 1; d < NPART; d <<= 1) {
        int v = 0;
        if (t < NPART && t >= d) v = incl[t - d];
        __syncthreads();
        if (t < NPART) incl[t] += v;
        __syncthreads();
    }
    if (t < NPART) cursor[t] = incl[t] - cnt[t];   // exclusive offset
    __syncthreads();

    for (int b = t; b < BATCH; b += 256) {
        int ind = randind[b];
        int pos = atomicAdd(&cursor[ind], 1);
        list[pos] = (b << 7) | ind;
        wout[b]   = p[ind];
        indout[b] = (float)ind;        // exact for 0..127
    }
}

// ---------------------------------------------------------------------------
// Compute: 2048 blocks x 128 threads, 2 sorted samples per block.
// Explicit 16-deep float4 staging -> ~16 loads in flight per wave.
// ---------------------------------------------------------------------------
__global__ __launch_bounds__(NDIM)
void mix_kernel(const float* __restrict__ gaussian,  // [BATCH, NDIM]
                const float* __restrict__ pos,       // [NPART, NDIM]
                const float* __restrict__ sigma,     // [NPART, NDIM, NDIM]
                const int*   __restrict__ list,      // [BATCH] packed, sorted
                float* __restrict__ out) {           // [BATCH, NDIM]
    const int g = blockIdx.x;
    // XCD-chunked bijective swizzle (NBLK % NXCD == 0): each XCD works a
    // contiguous chunk of sorted order -> ~16 particles (~1MB) per L2.
    const int cpx = NBLK / NXCD;
    const int sg  = (g % NXCD) * cpx + g / NXCD;
    const int p0  = sg * SPB;
    const int i   = threadIdx.x;

    const int e0 = list[p0], e1 = list[p0 + 1];     // uniform -> scalarized
    const int sid0 = e0 >> 7, ind0 = e0 & 127;
    const int sid1 = e1 >> 7, ind1 = e1 & 127;

    __shared__ float y[SPB][NDIM];
    y[0][i] = gaussian[sid0 * NDIM + i];
    y[1][i] = gaussian[sid1 * NDIM + i];
    __syncthreads();

    const float4* y40 = reinterpret_cast<const float4*>(y[0]);
    const float4* y41 = reinterpret_cast<const float4*>(y[1]);

    float acc0 = 0.f, acc1 = 0.f;

    if (ind0 == ind1) {   // same particle (~94% of blocks): share sigma row
        const float4* row = reinterpret_cast<const float4*>(
            sigma + ((size_t)ind0 * NDIM + i) * NDIM);
        #pragma unroll
        for (int r = 0; r < 2; ++r) {
            float4 sv[16];
            #pragma unroll
            for (int u = 0; u < 16; ++u) sv[u] = row[r * 16 + u];
            #pragma unroll
            for (int u = 0; u < 16; ++u) {
                float4 a = y40[r * 16 + u];
                float4 b = y41[r * 16 + u];
                acc0 += sv[u].x * a.x + sv[u].y * a.y + sv[u].z * a.z + sv[u].w * a.w;
                acc1 += sv[u].x * b.x + sv[u].y * b.y + sv[u].z * b.z + sv[u].w * b.w;
            }
        }
    } else {              // bucket boundary
        const float4* row0 = reinterpret_cast<const float4*>(
            sigma + ((size_t)ind0 * NDIM + i) * NDIM);
        const float4* row1 = reinterpret_cast<const float4*>(
            sigma + ((size_t)ind1 * NDIM + i) * NDIM);
        #pragma unroll
        for (int r = 0; r < 4; ++r) {
            float4 sv0[8], sv1[8];
            #pragma unroll
            for (int u = 0; u < 8; ++u) { sv0[u] = row0[r * 8 + u]; sv1[u] = row1[r * 8 + u]; }
            #pragma unroll
            for (int u = 0; u < 8; ++u) {
                float4 a = y40[r * 8 + u];
                float4 b = y41[r * 8 + u];
                acc0 += sv0[u].x * a.x + sv0[u].y * a.y + sv0[u].z * a.z + sv0[u].w * a.w;
                acc1 += sv1[u].x * b.x + sv1[u].y * b.y + sv1[u].z * b.z + sv1[u].w * b.w;
            }
        }
    }

    out[sid0 * NDIM + i] = pos[ind0 * NDIM + i] + acc0;
    out[sid1 * NDIM + i] = pos[ind1 * NDIM + i] + acc1;
}

extern "C" void kernel_launch(void* const* d_in, const int* in_sizes, int n_in,
                              void* d_out, int out_size, void* d_ws, size_t ws_size,
                              hipStream_t stream) {
    const float* gaussian = (const float*)d_in[0];   // [4096,128]
    const float* logp     = (const float*)d_in[1];   // [128,1]
    const float* pos      = (const float*)d_in[2];   // [128,128]
    const float* sigma    = (const float*)d_in[3];   // [128,128,128]
    const int*   randind  = (const int*)d_in[4];     // [4096]

    float* out    = (float*)d_out;            // [4096*128]
    float* wout   = out + BATCH * NDIM;       // [4096]
    float* indout = wout + BATCH;             // [4096]

    int* list = (int*)d_ws;                   // [4096] packed (sid<<7)|ind

    prep_kernel<<<1, 256, 0, stream>>>(logp, randind, list, wout, indout);
    mix_kernel<<<NBLK, NDIM, 0, stream>>>(gaussian, pos, sigma, list, out);
}